// Round 3
// baseline (6269.385 us; speedup 1.0000x reference)
//
#include <hip/hip_runtime.h>
#include <stdint.h>

#define B_ 128
#define T_ 512
#define H_ 256
#define K_ 512          // concat K (x|h or h1|h2)
#define NBLK 32         // blocks per layer
#define HS 8            // h-cols per block
#define SLAB64 8192     // u64 per t-slab: 128 rows * 64

typedef short bf16x8 __attribute__((ext_vector_type(8)));   // 8 bf16 = 4 VGPRs
typedef float f32x4 __attribute__((ext_vector_type(4)));

union U64V {            // two u64 bypass loads = one bf16x8 A-fragment
    unsigned long long u[2];
    bf16x8 v;
};

__device__ __forceinline__ unsigned short f2bf(float f) {
    union { float f; uint32_t u; } v; v.f = f;
    uint32_t u = v.u;
    return (unsigned short)((u + 0x7FFFu + ((u >> 16) & 1u)) >> 16);  // RNE
}
__device__ __forceinline__ float sigm(float x) { return 1.0f / (1.0f + __expf(-x)); }
__device__ __forceinline__ float tanh_(float x) { return 1.0f - 2.0f / (__expf(2.0f * x) + 1.0f); }

// ---- prep: x[b][t][f] fp32 -> xbf[t][b][f] bf16 ----
__global__ void k_prep_x(const float* __restrict__ x, unsigned short* __restrict__ xbf) {
    int idx = blockIdx.x * blockDim.x + threadIdx.x;   // over B*T*F/4
    int f4 = idx & 63;
    int t = (idx >> 6) & 511;
    int b = idx >> 15;
    float4 v = *(const float4*)(x + ((size_t)b * T_ + t) * H_ + f4 * 4);
    ushort4 o;
    o.x = f2bf(v.x); o.y = f2bf(v.y); o.z = f2bf(v.z); o.w = f2bf(v.w);
    *(ushort4*)(xbf + ((size_t)t * B_ + b) * H_ + f4 * 4) = o;
}

// ---- prep: Wt[col][k] bf16 (col<1024, k<512); k<256 from Wx, else Wh ----
__global__ void k_prep_w(const float* __restrict__ Wx, const float* __restrict__ Wh,
                         unsigned short* __restrict__ Wt) {
    int idx = blockIdx.x * blockDim.x + threadIdx.x;   // over 1024*512
    int k = idx & 511; int col = idx >> 9;
    float v = (k < 256) ? Wx[(size_t)k * 1024 + col] : Wh[(size_t)(k - 256) * 1024 + col];
    Wt[(size_t)col * 512 + k] = f2bf(v);
}

__global__ void k_prep_wd(const float* __restrict__ Wd, unsigned short* __restrict__ Wdt) {
    int idx = blockIdx.x * blockDim.x + threadIdx.x;   // 256*256
    int k = idx & 255; int col = idx >> 8;
    Wdt[(size_t)col * 256 + k] = f2bf(Wd[(size_t)k * 256 + col]);
}

// ---- persistent fused 2-layer LSTM recurrence, wave-autonomous handoff ----
// grid = 64 blocks x 256 thr: blocks [0,32) layer1 (A=[x_t ; h1_{t-1}]),
// [32,64) layer2 (A=[h1_t ; h2_{t-1}]). Block owns HS=8 h-cols.
// Wave w's MFMA A-rows are exactly the rows produced by wave w of every
// block, so handoff is per-wave: flags[layer][wave][block] = t+1 set by a
// plain bypass store after the wave's own h stores are acked (s_waitcnt 0).
// NO __syncthreads, NO atomic RMW, NO cache-wide fences anywhere.
__global__ __launch_bounds__(256, 1) void k_lstm(
    const unsigned short* __restrict__ xbf,
    const unsigned short* __restrict__ Wt1, const unsigned short* __restrict__ Wt2,
    const float* __restrict__ b0, const float* __restrict__ b1,
    unsigned long long* h1buf, unsigned long long* h2buf,
    unsigned long long* zslab, int* flags) {
    const int layer = blockIdx.x >> 5;
    const int blk = blockIdx.x & 31;
    const int hbase = blk * HS;
    const int tid = threadIdx.x;
    const int wave = tid >> 6;
    const int lane = tid & 63;
    const int quad = lane >> 4;
    const int l15 = lane & 15;
    const bool lo = (l15 < 8);

    const unsigned short* Wt = layer ? Wt2 : Wt1;
    const float* bias = layer ? b1 : b0;
    unsigned long long* hout = layer ? h2buf : h1buf;

    // poll target for this lane: layer0 -> own-layer flags, need t.
    // layer1 -> lanes 0-31 watch h1 flags (need t+1), lanes 32-63 watch own
    // h2 flags (need t).
    int* fl_own = flags + (layer * 4 + wave) * NBLK;            // producer slot base
    int* poll_p;
    int poll_add;
    if (layer == 0) {
        poll_p = flags + (0 * 4 + wave) * NBLK + (lane & 31);
        poll_add = 0;
    } else {
        if (lane < 32) { poll_p = flags + (0 * 4 + wave) * NBLK + lane;        poll_add = 1; }
        else           { poll_p = flags + (1 * 4 + wave) * NBLK + (lane - 32); poll_add = 0; }
    }

    // virtual cols: nt0 = [i-strip | f-strip], nt1 = [g-strip | o-strip]
    int col[2];
#pragma unroll
    for (int nt = 0; nt < 2; ++nt) {
        int g0 = nt * 512;
        col[nt] = lo ? (g0 + hbase + l15) : (g0 + 256 + hbase + (l15 - 8));
    }
    float bia[2]; bia[0] = bias[col[0]]; bia[1] = bias[col[1]];

    // B fragments register-resident for all 512 steps
    bf16x8 Bf[16][2];
#pragma unroll
    for (int kt = 0; kt < 16; ++kt)
#pragma unroll
        for (int nt = 0; nt < 2; ++nt)
            Bf[kt][nt] = *(const bf16x8*)(Wt + (size_t)col[nt] * K_ + kt * 32 + quad * 8);

    float creg[2][4];
#pragma unroll
    for (int m = 0; m < 2; ++m)
#pragma unroll
        for (int r = 0; r < 4; ++r) creg[m][r] = 0.f;

    const int rowbase = wave * 32;
    const f32x4 zero = {0.f, 0.f, 0.f, 0.f};

    for (int t = 0; t < T_; ++t) {
        f32x4 acc[2][2];
#pragma unroll
        for (int m = 0; m < 2; ++m) { acc[m][0] = zero; acc[m][1] = zero; }

        U64V fh[2][8];

        if (layer == 0) {
            // ---- x-part first: cached loads, no dependency -> overlaps wait
            const unsigned short* A0 = xbf + (size_t)t * B_ * H_;
#pragma unroll
            for (int m = 0; m < 2; ++m) {
                const unsigned short* pa0 = A0 + (size_t)(rowbase + m * 16 + l15) * H_ + quad * 8;
#pragma unroll
                for (int kt = 0; kt < 8; ++kt) {
                    bf16x8 a = *(const bf16x8*)(pa0 + kt * 32);
                    acc[m][0] = __builtin_amdgcn_mfma_f32_16x16x32_bf16(a, Bf[kt][0], acc[m][0], 0, 0, 0);
                    acc[m][1] = __builtin_amdgcn_mfma_f32_16x16x32_bf16(a, Bf[kt][1], acc[m][1], 0, 0, 0);
                }
            }
            // ---- wave-level poll: all 32 producer flags of my wave-row-group
            {
                int need = t + poll_add;
                bool ok;
                do {
                    ok = (__hip_atomic_load(poll_p, __ATOMIC_RELAXED, __HIP_MEMORY_SCOPE_AGENT) >= need);
                } while (!__all(ok));
            }
            const unsigned long long* ps = (t == 0) ? zslab : (h1buf + (size_t)(t - 1) * SLAB64);
#pragma unroll
            for (int m = 0; m < 2; ++m) {
                const unsigned long long* pr = ps + (size_t)(rowbase + m * 16 + l15) * 64 + quad * 2;
#pragma unroll
                for (int kt = 0; kt < 8; ++kt) {
                    fh[m][kt].u[0] = __hip_atomic_load(pr + kt * 8,     __ATOMIC_RELAXED, __HIP_MEMORY_SCOPE_AGENT);
                    fh[m][kt].u[1] = __hip_atomic_load(pr + kt * 8 + 1, __ATOMIC_RELAXED, __HIP_MEMORY_SCOPE_AGENT);
                }
            }
#pragma unroll
            for (int m = 0; m < 2; ++m)
#pragma unroll
                for (int kt = 0; kt < 8; ++kt) {
                    acc[m][0] = __builtin_amdgcn_mfma_f32_16x16x32_bf16(fh[m][kt].v, Bf[8 + kt][0], acc[m][0], 0, 0, 0);
                    acc[m][1] = __builtin_amdgcn_mfma_f32_16x16x32_bf16(fh[m][kt].v, Bf[8 + kt][1], acc[m][1], 0, 0, 0);
                }
        } else {
            // ---- single combined poll: h1[t] ready AND own h2[t-1] ready
            {
                int need = t + poll_add;
                bool ok;
                do {
                    ok = (__hip_atomic_load(poll_p, __ATOMIC_RELAXED, __HIP_MEMORY_SCOPE_AGENT) >= need);
                } while (!__all(ok));
            }
            const unsigned long long* ps0 = h1buf + (size_t)t * SLAB64;
            const unsigned long long* ps1 = (t == 0) ? zslab : (h2buf + (size_t)(t - 1) * SLAB64);
            U64V fg[2][8];
#pragma unroll
            for (int m = 0; m < 2; ++m) {
                const unsigned long long* pr0 = ps0 + (size_t)(rowbase + m * 16 + l15) * 64 + quad * 2;
                const unsigned long long* pr1 = ps1 + (size_t)(rowbase + m * 16 + l15) * 64 + quad * 2;
#pragma unroll
                for (int kt = 0; kt < 8; ++kt) {
                    fh[m][kt].u[0] = __hip_atomic_load(pr0 + kt * 8,     __ATOMIC_RELAXED, __HIP_MEMORY_SCOPE_AGENT);
                    fh[m][kt].u[1] = __hip_atomic_load(pr0 + kt * 8 + 1, __ATOMIC_RELAXED, __HIP_MEMORY_SCOPE_AGENT);
                    fg[m][kt].u[0] = __hip_atomic_load(pr1 + kt * 8,     __ATOMIC_RELAXED, __HIP_MEMORY_SCOPE_AGENT);
                    fg[m][kt].u[1] = __hip_atomic_load(pr1 + kt * 8 + 1, __ATOMIC_RELAXED, __HIP_MEMORY_SCOPE_AGENT);
                }
            }
#pragma unroll
            for (int m = 0; m < 2; ++m)
#pragma unroll
                for (int kt = 0; kt < 8; ++kt) {
                    acc[m][0] = __builtin_amdgcn_mfma_f32_16x16x32_bf16(fh[m][kt].v, Bf[kt][0], acc[m][0], 0, 0, 0);
                    acc[m][1] = __builtin_amdgcn_mfma_f32_16x16x32_bf16(fh[m][kt].v, Bf[kt][1], acc[m][1], 0, 0, 0);
                    acc[m][0] = __builtin_amdgcn_mfma_f32_16x16x32_bf16(fg[m][kt].v, Bf[8 + kt][0], acc[m][0], 0, 0, 0);
                    acc[m][1] = __builtin_amdgcn_mfma_f32_16x16x32_bf16(fg[m][kt].v, Bf[8 + kt][1], acc[m][1], 0, 0, 0);
                }
        }

        // ---- gates + pack + bypass store (wave-local, no barrier) ----
        unsigned long long* hdst = hout + (size_t)t * SLAB64;
#pragma unroll
        for (int m = 0; m < 2; ++m) {
#pragma unroll
            for (int r = 0; r < 4; ++r) {
                float a0 = acc[m][0][r] + bia[0];   // i (lo) / f (hi)
                float a1 = acc[m][1][r] + bia[1];   // g (lo) / o (hi)
                float p0 = __shfl_xor(a0, 8);
                float p1 = __shfl_xor(a1, 8);
                float zi = lo ? a0 : p0;
                float zf = lo ? p0 : a0;
                float zg = lo ? a1 : p1;
                float zo = lo ? p1 : a1;
                float gi = sigm(zi), gf = sigm(zf), gg = tanh_(zg), go = sigm(zo);
                float c = gf * creg[m][r] + gi * gg;
                creg[m][r] = c;
                float h = go * tanh_(c);
                // pack 4 ascending cols into one u64 (byte-identical to bf16 row)
                unsigned int hb = f2bf(h);
                unsigned int pp = hb | (((unsigned int)__shfl_xor((int)hb, 1)) << 16);
                unsigned long long hi32 = (unsigned int)__shfl_xor((int)pp, 2);
                unsigned long long w = ((unsigned long long)pp) | (hi32 << 32);
                if (lo && ((l15 & 3) == 0)) {
                    int row = rowbase + m * 16 + quad * 4 + r;
                    __hip_atomic_store(hdst + (size_t)row * 64 + ((hbase + l15) >> 2), w,
                                       __ATOMIC_RELAXED, __HIP_MEMORY_SCOPE_AGENT);
                }
            }
        }
        __builtin_amdgcn_s_waitcnt(0);   // drain: wave's h stores acked at L3
        if (lane == 0)
            __hip_atomic_store(fl_own + blk, t + 1, __ATOMIC_RELAXED, __HIP_MEMORY_SCOPE_AGENT);
    }
}

// ---- Dense(tanh) + LayerNorm, one block per t (128 rows), full N=256 in regs ----
__global__ __launch_bounds__(256, 2) void k_dense_ln(
    const unsigned short* __restrict__ h2buf, const unsigned short* __restrict__ Wdt,
    const float* __restrict__ bd, const float* __restrict__ gamma,
    const float* __restrict__ beta, float* __restrict__ out) {
    const int t = blockIdx.x;
    const int tid = threadIdx.x;
    const int wave = tid >> 6, lane = tid & 63, quad = lane >> 4, l15 = lane & 15;
    const unsigned short* A = h2buf + (size_t)t * B_ * H_;
    const f32x4 zero = {0.f, 0.f, 0.f, 0.f};

    f32x4 acc[2][16];
#pragma unroll
    for (int m = 0; m < 2; ++m)
#pragma unroll
        for (int n = 0; n < 16; ++n) acc[m][n] = zero;

#pragma unroll
    for (int kt = 0; kt < 8; ++kt) {
        bf16x8 a[2];
#pragma unroll
        for (int m = 0; m < 2; ++m) {
            int row = wave * 32 + m * 16 + l15;
            a[m] = *(const bf16x8*)(A + (size_t)row * H_ + kt * 32 + quad * 8);
        }
#pragma unroll
        for (int n = 0; n < 16; ++n) {
            bf16x8 b = *(const bf16x8*)(Wdt + (size_t)(n * 16 + l15) * H_ + kt * 32 + quad * 8);
            acc[0][n] = __builtin_amdgcn_mfma_f32_16x16x32_bf16(a[0], b, acc[0][n], 0, 0, 0);
            acc[1][n] = __builtin_amdgcn_mfma_f32_16x16x32_bf16(a[1], b, acc[1][n], 0, 0, 0);
        }
    }

    float gm[16], bt[16], bdv[16];
#pragma unroll
    for (int n = 0; n < 16; ++n) {
        int c = n * 16 + l15;
        gm[n] = gamma[c]; bt[n] = beta[c]; bdv[n] = bd[c];
    }
#pragma unroll
    for (int m = 0; m < 2; ++m) {
#pragma unroll
        for (int r = 0; r < 4; ++r) {
            float v[16], s = 0.f, sq = 0.f;
#pragma unroll
            for (int n = 0; n < 16; ++n) {
                float x = tanh_(acc[m][n][r] + bdv[n]);
                v[n] = x; s += x; sq += x * x;
            }
#pragma unroll
            for (int off = 1; off < 16; off <<= 1) {
                s += __shfl_xor(s, off);
                sq += __shfl_xor(sq, off);
            }
            float mu = s * (1.f / 256.f);
            float var = sq * (1.f / 256.f) - mu * mu;
            float rs = rsqrtf(var + 1e-3f);
            int row = wave * 32 + m * 16 + quad * 4 + r;   // batch index
            float* po = out + (size_t)row * (T_ * H_) + (size_t)t * H_;
#pragma unroll
            for (int n = 0; n < 16; ++n)
                po[n * 16 + l15] = (v[n] - mu) * rs * gm[n] + bt[n];
        }
    }
}

extern "C" void kernel_launch(void* const* d_in, const int* in_sizes, int n_in,
                              void* d_out, int out_size, void* d_ws, size_t ws_size,
                              hipStream_t stream) {
    const float* x     = (const float*)d_in[0];
    const float* W0    = (const float*)d_in[1];
    const float* U0    = (const float*)d_in[2];
    const float* b0    = (const float*)d_in[3];
    const float* W1    = (const float*)d_in[4];
    const float* U1    = (const float*)d_in[5];
    const float* b1    = (const float*)d_in[6];
    const float* Wd    = (const float*)d_in[7];
    const float* bd    = (const float*)d_in[8];
    const float* gamma = (const float*)d_in[9];
    const float* beta  = (const float*)d_in[10];
    float* out = (float*)d_out;

    char* ws = (char*)d_ws;
    unsigned short* xbf      = (unsigned short*)(ws);               // 32 MB  [T][B][F] bf16
    unsigned long long* h1b  = (unsigned long long*)(ws + 33554432);// 32 MB  [T][B][H/4] u64-packed bf16
    unsigned long long* h2b  = (unsigned long long*)(ws + 67108864);// 32 MB
    unsigned short* Wt1 = (unsigned short*)(ws + 100663296);        // 1 MB   [1024][512] bf16
    unsigned short* Wt2 = (unsigned short*)(ws + 101711872);        // 1 MB
    unsigned short* Wdt = (unsigned short*)(ws + 102760448);        // 128 KB [256][256] bf16
    unsigned long long* zsl = (unsigned long long*)(ws + 102891520);// 64 KB zero slab
    int* flags          = (int*)(ws + 102957056);                   // 1 KB   [2][4][32]

    hipMemsetAsync(zsl, 0, 65536 + 4096, stream);                   // zero slab + flags
    k_prep_x<<<16384, 256, 0, stream>>>(x, xbf);
    k_prep_w<<<2048, 256, 0, stream>>>(W0, U0, Wt1);
    k_prep_w<<<2048, 256, 0, stream>>>(W1, U1, Wt2);
    k_prep_wd<<<256, 256, 0, stream>>>(Wd, Wdt);
    k_lstm<<<64, 256, 0, stream>>>(xbf, Wt1, Wt2, b0, b1, h1b, h2b, zsl, flags);
    k_dense_ln<<<512, 256, 0, stream>>>((const unsigned short*)h2b, Wdt, bd, gamma, beta, out);
}

// Round 5
// 2882.738 us; speedup vs baseline: 2.1748x; 2.1748x over previous
//
#include <hip/hip_runtime.h>
#include <stdint.h>

#define B_ 128
#define T_ 512
#define H_ 256
#define CH 128           // timesteps per chunk (xz slab = 32 MB)
#define RB 32            // rec blocks per layer (4 batch rows each)

typedef short bf16x8 __attribute__((ext_vector_type(8)));   // 8 bf16 = 4 VGPRs
typedef float f32x4 __attribute__((ext_vector_type(4)));
typedef int   i32x4 __attribute__((ext_vector_type(4)));

__device__ __forceinline__ unsigned short f2bf(float f) {
    union { float f; uint32_t u; } v; v.f = f;
    uint32_t u = v.u;
    return (unsigned short)((u + 0x7FFFu + ((u >> 16) & 1u)) >> 16);  // RNE
}
__device__ __forceinline__ float bf2f(unsigned int b) {
    union { uint32_t u; float f; } v; v.u = (b & 0xFFFFu) << 16; return v.f;
}
__device__ __forceinline__ float sigm(float x) { return 1.0f / (1.0f + __expf(-x)); }
__device__ __forceinline__ float tanh_(float x) { return 1.0f - 2.0f / (__expf(2.0f * x) + 1.0f); }

// ---- prep: x[b][t][f] fp32 -> xbf[t][b][f] bf16 ----
__global__ void k_prep_x(const float* __restrict__ x, unsigned short* __restrict__ xbf) {
    int idx = blockIdx.x * blockDim.x + threadIdx.x;   // over B*T*F/4
    int f4 = idx & 63;
    int t = (idx >> 6) & 511;
    int b = idx >> 15;
    float4 v = *(const float4*)(x + ((size_t)b * T_ + t) * H_ + f4 * 4);
    ushort4 o;
    o.x = f2bf(v.x); o.y = f2bf(v.y); o.z = f2bf(v.z); o.w = f2bf(v.w);
    *(ushort4*)(xbf + ((size_t)t * B_ + b) * H_ + f4 * 4) = o;
}

// ---- prep: in [256][1024] fp32 -> out[col][k] bf16 ----
__global__ void k_prep_w(const float* __restrict__ in, unsigned short* __restrict__ out) {
    int idx = blockIdx.x * blockDim.x + threadIdx.x;   // 1024*256
    int k = idx & 255; int col = idx >> 8;
    out[(size_t)col * 256 + k] = f2bf(in[(size_t)k * 1024 + col]);
}

__global__ void k_prep_wd(const float* __restrict__ Wd, unsigned short* __restrict__ Wdt) {
    int idx = blockIdx.x * blockDim.x + threadIdx.x;   // 256*256
    int k = idx & 255; int col = idx >> 8;
    Wdt[(size_t)col * 256 + k] = f2bf(Wd[(size_t)k * 256 + col]);
}

// ---- absmax of U (262144 fp32) -> slot (float bits via int atomicMax) ----
__global__ void k_umax(const float* __restrict__ in, float* __restrict__ slot) {
    float m = 0.f;
    for (int i = blockIdx.x * blockDim.x + threadIdx.x; i < 262144; i += gridDim.x * blockDim.x)
        m = fmaxf(m, fabsf(in[i]));
#pragma unroll
    for (int off = 1; off < 64; off <<= 1) m = fmaxf(m, __shfl_xor(m, off));
    if ((threadIdx.x & 63) == 0) atomicMax((int*)slot, __float_as_int(m));
}

// ---- quantize U: in [256][1024] fp32 -> out[col][k] i8 ----
__global__ void k_prep_u(const float* __restrict__ in, const float* __restrict__ umax,
                         signed char* __restrict__ out) {
    int idx = blockIdx.x * blockDim.x + threadIdx.x;   // 1024*256
    int k = idx & 255; int col = idx >> 8;
    float s = 127.f / *umax;
    float v = in[(size_t)k * 1024 + col] * s;
    out[(size_t)col * 256 + k] = (signed char)__float2int_rn(fminf(fmaxf(v, -127.f), 127.f));
}

// ---- input-projection GEMM for one 128-t chunk:
// A[tl][128][256] bf16 x Bt[1024][256] + bias -> xz swizzled bf16:
// elem addr = tl*131072 + rg*16384 + wr*4096 + n*256 + (quad*16+l15)*4 + r
// holding z[row = rg*16 + quad*4 + r][col = g*256 + wr*64 + s*16 + l15], n = g*4+s.
__global__ __launch_bounds__(256, 2) void k_gemm(
    const unsigned short* __restrict__ A, const unsigned short* __restrict__ Bt,
    const float* __restrict__ bias, unsigned short* __restrict__ xz) {
    const int tl = blockIdx.x >> 2, nq = blockIdx.x & 3;
    const int tid = threadIdx.x;
    const int wave = tid >> 6, lane = tid & 63, quad = lane >> 4, l15 = lane & 15;
    const f32x4 zero = {0.f, 0.f, 0.f, 0.f};
    f32x4 acc[2][16];
#pragma unroll
    for (int m = 0; m < 2; ++m)
#pragma unroll
        for (int n = 0; n < 16; ++n) acc[m][n] = zero;

#pragma unroll
    for (int kt = 0; kt < 8; ++kt) {
        bf16x8 a0 = *(const bf16x8*)(A + ((size_t)(tl * 128 + wave * 32 + l15)) * 256 + kt * 32 + quad * 8);
        bf16x8 a1 = *(const bf16x8*)(A + ((size_t)(tl * 128 + wave * 32 + 16 + l15)) * 256 + kt * 32 + quad * 8);
#pragma unroll
        for (int ntl = 0; ntl < 16; ++ntl) {
            bf16x8 b = *(const bf16x8*)(Bt + ((size_t)(nq * 256 + ntl * 16 + l15)) * 256 + kt * 32 + quad * 8);
            acc[0][ntl] = __builtin_amdgcn_mfma_f32_16x16x32_bf16(a0, b, acc[0][ntl], 0, 0, 0);
            acc[1][ntl] = __builtin_amdgcn_mfma_f32_16x16x32_bf16(a1, b, acc[1][ntl], 0, 0, 0);
        }
    }
#pragma unroll
    for (int ntl = 0; ntl < 16; ++ntl) {
        int c0 = nq * 256 + ntl * 16;
        float bv = bias[c0 + l15];
        int wr = ntl >> 2, s = ntl & 3;
        int n = nq * 4 + s;
#pragma unroll
        for (int mt = 0; mt < 2; ++mt) {
            int rg = wave * 2 + mt;
            unsigned long long pk = 0;
#pragma unroll
            for (int r = 0; r < 4; ++r)
                pk |= ((unsigned long long)f2bf(acc[mt][ntl][r] + bv)) << (16 * r);
            *(unsigned long long*)(xz + (((size_t)(tl * 8 + rg) * 4 + wr) * 16 + n) * 256 + lane * 4) = pk;
        }
    }
}

// ---- LSTM recurrence chunk: i8 MFMA, U fully register-resident ----
// grid = 32 blocks x 256 thr; block owns batch rows [4*blk, 4*blk+4).
// Wave w covers cols w*64+s*16+l15 of each gate g; tiles n = g*4+s.
// z-exchange through LDS spreads gate math over all lanes (row = quad).
__global__ __launch_bounds__(256, 1) void k_rec(
    const signed char* __restrict__ Ui8,     // [1024][256] i8
    const unsigned short* __restrict__ xz,   // chunk, swizzled
    const float* __restrict__ uscale,
    unsigned short* __restrict__ hout,       // [T][128][256] bf16
    float* __restrict__ cstate,              // [32][256][4]
    int t0) {
    __shared__ __align__(16) int zbuf[4096];             // [w][n][l15][r] = 16 KB
    __shared__ __align__(16) signed char hbuf[2][16 * 272];  // i8 h ping-pong
    const int blk = blockIdx.x;
    const int tid = threadIdx.x;
    const int w = tid >> 6, lane = tid & 63, quad = lane >> 4, l15 = lane & 15;
    const int sh = quad * 16;

    // U fragments: 16 n-tiles x 4 kt x int4 = 256 VGPR, resident all steps
    i32x4 Bf[16][4];
#pragma unroll
    for (int n = 0; n < 16; ++n) {
        int col = (n >> 2) * 256 + w * 64 + (n & 3) * 16 + l15;
#pragma unroll
        for (int kt = 0; kt < 4; ++kt)
            Bf[n][kt] = *(const i32x4*)(Ui8 + (size_t)col * 256 + kt * 64 + quad * 16);
    }

    // zero both h buffers (rows 4..15 stay zero forever)
    for (int i = tid; i < 2176; i += 256) ((int*)hbuf)[i] = 0;

    float cst[4];
    if (t0 > 0) {
#pragma unroll
        for (int s = 0; s < 4; ++s) {
            float h = bf2f(hout[((size_t)(t0 - 1) * 128 + blk * 4 + quad) * 256 + w * 64 + s * 16 + l15]);
            hbuf[0][quad * 272 + w * 64 + s * 16 + l15] = (signed char)__float2int_rn(h * 127.f);
            cst[s] = cstate[((size_t)blk * 256 + tid) * 4 + s];
        }
    } else {
#pragma unroll
        for (int s = 0; s < 4; ++s) cst[s] = 0.f;
    }
    const float SUH = (*uscale) * (1.f / 16129.f);   // (umax/127) * (1/127)
    __syncthreads();

    const i32x4 zeroi = {0, 0, 0, 0};
    int p = 0;
#pragma unroll 1
    for (int tl = 0; tl < CH; ++tl) {
        // xz loads: no dependency, fire early (latency hidden behind MFMA)
        const unsigned short* xb = xz + (size_t)tl * 131072 + (blk >> 2) * 16384
                                      + w * 4096 + (blk & 3) * 64 + l15 * 4;
        unsigned long long xu[16];
#pragma unroll
        for (int n = 0; n < 16; ++n)
            xu[n] = *(const unsigned long long*)(xb + n * 256);

        // A fragments from i8 h ping-pong (rows 4..15 are zero padding)
        const signed char* hb = hbuf[p];
        i32x4 Af[4];
#pragma unroll
        for (int kt = 0; kt < 4; ++kt)
            Af[kt] = *(const i32x4*)(hb + l15 * 272 + kt * 64 + quad * 16);

        i32x4 acc[16];
#pragma unroll
        for (int n = 0; n < 16; ++n) acc[n] = zeroi;
#pragma unroll
        for (int kt = 0; kt < 4; ++kt) {
            i32x4 a = Af[kt];
#pragma unroll
            for (int n = 0; n < 16; ++n)
                acc[n] = __builtin_amdgcn_mfma_i32_16x16x64_i8(a, Bf[n][kt], acc[n], 0, 0, 0);
        }

        // z-exchange (wave-local: writer quad0 lanes, readers all lanes)
        if (quad == 0) {
#pragma unroll
            for (int n = 0; n < 16; ++n)
                *(i32x4*)(zbuf + ((w * 16 + n) * 16 + l15) * 4) = acc[n];
        }
        float zv[16];
#pragma unroll
        for (int n = 0; n < 16; ++n) {
            int zi = zbuf[((w * 16 + n) * 16 + l15) * 4 + quad];
            zv[n] = (float)zi * SUH + bf2f((unsigned int)(xu[n] >> sh));
        }

        // gates: this lane owns (row = quad, cols w*64 + s*16 + l15)
        unsigned short* hO = hout + ((size_t)((t0 + tl) * 128 + blk * 4 + quad)) * 256 + w * 64 + l15;
        signed char* hw = hbuf[p ^ 1];
#pragma unroll
        for (int s = 0; s < 4; ++s) {
            float c = sigm(zv[4 + s]) * cst[s] + sigm(zv[s]) * tanh_(zv[8 + s]);
            cst[s] = c;
            float h = sigm(zv[12 + s]) * tanh_(c);
            hO[s * 16] = f2bf(h);
            hw[quad * 272 + w * 64 + s * 16 + l15] = (signed char)__float2int_rn(h * 127.f);
        }
        __syncthreads();
        p ^= 1;
    }
#pragma unroll
    for (int s = 0; s < 4; ++s)
        cstate[((size_t)blk * 256 + tid) * 4 + s] = cst[s];
}

// ---- Dense(tanh) + LayerNorm, one block per t (128 rows), full N=256 in regs ----
__global__ __launch_bounds__(256, 2) void k_dense_ln(
    const unsigned short* __restrict__ h2buf, const unsigned short* __restrict__ Wdt,
    const float* __restrict__ bd, const float* __restrict__ gamma,
    const float* __restrict__ beta, float* __restrict__ out) {
    const int t = blockIdx.x;
    const int tid = threadIdx.x;
    const int wave = tid >> 6, lane = tid & 63, quad = lane >> 4, l15 = lane & 15;
    const unsigned short* A = h2buf + (size_t)t * B_ * H_;
    const f32x4 zero = {0.f, 0.f, 0.f, 0.f};

    f32x4 acc[2][16];
#pragma unroll
    for (int m = 0; m < 2; ++m)
#pragma unroll
        for (int n = 0; n < 16; ++n) acc[m][n] = zero;

#pragma unroll
    for (int kt = 0; kt < 8; ++kt) {
        bf16x8 a[2];
#pragma unroll
        for (int m = 0; m < 2; ++m) {
            int row = wave * 32 + m * 16 + l15;
            a[m] = *(const bf16x8*)(A + (size_t)row * H_ + kt * 32 + quad * 8);
        }
#pragma unroll
        for (int n = 0; n < 16; ++n) {
            bf16x8 b = *(const bf16x8*)(Wdt + (size_t)(n * 16 + l15) * H_ + kt * 32 + quad * 8);
            acc[0][n] = __builtin_amdgcn_mfma_f32_16x16x32_bf16(a[0], b, acc[0][n], 0, 0, 0);
            acc[1][n] = __builtin_amdgcn_mfma_f32_16x16x32_bf16(a[1], b, acc[1][n], 0, 0, 0);
        }
    }

    float gm[16], bt[16], bdv[16];
#pragma unroll
    for (int n = 0; n < 16; ++n) {
        int c = n * 16 + l15;
        gm[n] = gamma[c]; bt[n] = beta[c]; bdv[n] = bd[c];
    }
#pragma unroll
    for (int m = 0; m < 2; ++m) {
#pragma unroll
        for (int r = 0; r < 4; ++r) {
            float v[16], s = 0.f, sq = 0.f;
#pragma unroll
            for (int n = 0; n < 16; ++n) {
                float x = tanh_(acc[m][n][r] + bdv[n]);
                v[n] = x; s += x; sq += x * x;
            }
#pragma unroll
            for (int off = 1; off < 16; off <<= 1) {
                s += __shfl_xor(s, off);
                sq += __shfl_xor(sq, off);
            }
            float mu = s * (1.f / 256.f);
            float var = sq * (1.f / 256.f) - mu * mu;
            float rs = rsqrtf(var + 1e-3f);
            int row = wave * 32 + m * 16 + quad * 4 + r;   // batch index
            float* po = out + (size_t)row * (T_ * H_) + (size_t)t * H_;
#pragma unroll
            for (int n = 0; n < 16; ++n)
                po[n * 16 + l15] = (v[n] - mu) * rs * gm[n] + bt[n];
        }
    }
}

extern "C" void kernel_launch(void* const* d_in, const int* in_sizes, int n_in,
                              void* d_out, int out_size, void* d_ws, size_t ws_size,
                              hipStream_t stream) {
    const float* x     = (const float*)d_in[0];
    const float* W0    = (const float*)d_in[1];
    const float* U0    = (const float*)d_in[2];
    const float* b0    = (const float*)d_in[3];
    const float* W1    = (const float*)d_in[4];
    const float* U1    = (const float*)d_in[5];
    const float* b1    = (const float*)d_in[6];
    const float* Wd    = (const float*)d_in[7];
    const float* bd    = (const float*)d_in[8];
    const float* gamma = (const float*)d_in[9];
    const float* beta  = (const float*)d_in[10];
    float* out = (float*)d_out;

    char* ws = (char*)d_ws;
    unsigned short* buf0 = (unsigned short*)(ws);                  // 32 MB: xbf, later h2
    unsigned short* xzs  = (unsigned short*)(ws + (32u << 20));    // 32 MB: per-chunk xz
    unsigned short* h1   = (unsigned short*)(ws + (64u << 20));    // 32 MB
    unsigned short* Wt0  = (unsigned short*)(ws + (96u << 20));            // 512 KB
    unsigned short* Wt1  = (unsigned short*)(ws + (96u << 20) + 524288);   // 512 KB
    signed char*    Ui0  = (signed char*)  (ws + (96u << 20) + 1048576);   // 256 KB
    signed char*    Ui1  = (signed char*)  (ws + (96u << 20) + 1310720);   // 256 KB
    unsigned short* Wdt  = (unsigned short*)(ws + (96u << 20) + 1572864);  // 128 KB
    float*          sc   = (float*)        (ws + (96u << 20) + 1703936);   // 2 slots
    float*          cbuf = (float*)        (ws + (96u << 20) + 1704448);   // 128 KB

    hipMemsetAsync(sc, 0, 64, stream);
    k_prep_x<<<16384, 256, 0, stream>>>(x, buf0);
    k_prep_w<<<1024, 256, 0, stream>>>(W0, Wt0);
    k_prep_w<<<1024, 256, 0, stream>>>(W1, Wt1);
    k_prep_wd<<<256, 256, 0, stream>>>(Wd, Wdt);
    k_umax<<<256, 256, 0, stream>>>(U0, sc);
    k_umax<<<256, 256, 0, stream>>>(U1, sc + 1);
    k_prep_u<<<1024, 256, 0, stream>>>(U0, sc, Ui0);
    k_prep_u<<<1024, 256, 0, stream>>>(U1, sc + 1, Ui1);

    for (int c = 0; c < 4; ++c) {
        k_gemm<<<CH * 4, 256, 0, stream>>>(buf0 + (size_t)c * CH * 32768, Wt0, b0, xzs);
        k_rec<<<RB, 256, 0, stream>>>(Ui0, xzs, sc, h1, cbuf, c * CH);
    }
    for (int c = 0; c < 4; ++c) {
        k_gemm<<<CH * 4, 256, 0, stream>>>(h1 + (size_t)c * CH * 32768, Wt1, b1, xzs);
        k_rec<<<RB, 256, 0, stream>>>(Ui1, xzs, sc + 1, buf0, cbuf, c * CH);
    }
    k_dense_ln<<<512, 256, 0, stream>>>(buf0, Wdt, bd, gamma, beta, out);
}